// Round 6
// baseline (508.756 us; speedup 1.0000x reference)
//
#include <hip/hip_runtime.h>

#define N_NODES 131072
#define BGRAPHS 512
#define FDIM    512
#define HDIM    256
#define NPG     256
#define KSEL    128
#define STAGES  16                 // K = 512 / 32
#define BSTAGE_UNITS 3072          // bf16x8 units per K-stage of B (3 p * 2 q * 8 nt * 64 lanes)

typedef __attribute__((ext_vector_type(8)))  short bf16x8;
typedef __attribute__((ext_vector_type(16))) float f32x16;

// RNE float -> bf16 (bit trick), also returns the bf16 value as float
__device__ __forceinline__ unsigned short bf16_rne(float f, float* back) {
    unsigned u = __float_as_uint(f);
    unsigned r = u + 0x7FFFu + ((u >> 16) & 1u);
    unsigned short h = (unsigned short)(r >> 16);
    *back = __uint_as_float(((unsigned)h) << 16);
    return h;
}

// split 8 fp32 -> 3 bf16x8 planes (exact Dekker residuals)
__device__ __forceinline__ void split8(const float4& a, const float4& b,
                                       bf16x8& H, bf16x8& M, bf16x8& L) {
    float v[8] = {a.x, a.y, a.z, a.w, b.x, b.y, b.z, b.w};
    #pragma unroll
    for (int j = 0; j < 8; ++j) {
        float f1, f2, f3;
        unsigned short h1 = bf16_rne(v[j], &f1);
        float r1 = v[j] - f1;
        unsigned short h2 = bf16_rne(r1, &f2);
        float r2 = r1 - f2;
        unsigned short h3 = bf16_rne(r2, &f3);
        H[j] = (short)h1; M[j] = (short)h2; L[j] = (short)h3;
    }
}

// ---------------------------------------------------------------------------
// K0: split W1 (fp32 [512][256]) into 3 bf16 planes in MFMA B-fragment order.
// uid = s*3072 + ((q*3 + p)*8 + nt)*64 + lane, 8 bf16 each,
// elem j = W1[s*32 + q*16 + (lane>>5)*8 + j][nt*32 + (lane&31)]  (split p).
// ---------------------------------------------------------------------------
__global__ __launch_bounds__(256)
void split_w1_kernel(const float* __restrict__ W1, unsigned short* __restrict__ wsB)
{
    const int uid  = blockIdx.x * 256 + threadIdx.x;     // 0..49151
    const int lane = uid & 63;
    int t = uid >> 6;
    const int nt = t & 7;  t >>= 3;
    const int p  = t % 3;  t /= 3;
    const int q  = t & 1;
    const int s  = t >> 1;
    const int n  = nt * 32 + (lane & 31);
    const int k0 = s * 32 + q * 16 + (lane >> 5) * 8;

    bf16x8 v;
    #pragma unroll
    for (int j = 0; j < 8; ++j) {
        float w = W1[(size_t)(k0 + j) * HDIM + n];
        float f1, f2, f3;
        unsigned short h1 = bf16_rne(w, &f1);
        float r1 = w - f1;
        unsigned short h2 = bf16_rne(r1, &f2);
        float r2 = r1 - f2;
        unsigned short h3 = bf16_rne(r2, &f3);
        v[j] = (short)(p == 0 ? h1 : (p == 1 ? h2 : h3));
    }
    *(bf16x8*)(wsB + (size_t)uid * 8) = v;
}

// ---------------------------------------------------------------------------
// K1 (FUSED, barrier-free K-loop): one block per graph, 512 threads = 8 waves.
// GEMM phase uses NO LDS and NO barriers: B fragments load directly
// global->VGPR from the frag-ordered wsB (L2-hot, 768 KB), A loads
// global->VGPR and is split per-wave in registers. Waves drift freely so the
// CU-shared MFMA pipe stays fed. LDS (5.6 KB) only for the epilogue.
// ---------------------------------------------------------------------------
__global__ __launch_bounds__(512, 2)
void fused_kernel(const float* __restrict__ x,
                  const unsigned short* __restrict__ wsB,
                  const float* __restrict__ b1, const float* __restrict__ W2,
                  const float* __restrict__ b2,
                  float* __restrict__ pooled, float* __restrict__ mask_out,
                  float* __restrict__ loss_per_g)
{
    __shared__ float Sp[2 * NPG];
    __shared__ float sv[NPG];
    __shared__ int   selr[KSEL];
    __shared__ float redT[NPG];
    __shared__ float redS[NPG];

    const int g    = blockIdx.x;
    const int tid  = threadIdx.x;
    const int lane = tid & 63;
    const int wv   = tid >> 6;        // 0..7
    const int wy   = wv & 3;          // row quarter (64 rows)
    const int wx   = wv >> 2;         // col half (128 cols)
    const int l31  = lane & 31;
    const int lh   = lane >> 5;

    // A row pointers for this lane's two m-tiles
    const float* aRow0 = x + (size_t)(g * NPG + wy * 64 + l31) * FDIM;
    const float* aRow1 = aRow0 + (size_t)32 * FDIM;

    f32x16 acc[2][4];
    #pragma unroll
    for (int a = 0; a < 2; ++a)
        #pragma unroll
        for (int b = 0; b < 4; ++b)
            #pragma unroll
            for (int rr = 0; rr < 16; ++rr) acc[a][b][rr] = 0.f;

    // ---- barrier-free main K loop
    for (int s = 0; s < STAGES; ++s) {
        #pragma unroll
        for (int q = 0; q < 2; ++q) {
            const int ko = s * 32 + q * 16 + lh * 8;
            // A raw loads (4x dwordx4)
            const float4 xa0 = *(const float4*)(aRow0 + ko);
            const float4 xb0 = *(const float4*)(aRow0 + ko + 4);
            const float4 xa1 = *(const float4*)(aRow1 + ko);
            const float4 xb1 = *(const float4*)(aRow1 + ko + 4);
            // B fragment loads (12x dwordx4, lane-contiguous, L2-hot)
            const bf16x8* Bq = (const bf16x8*)wsB
                             + (size_t)s * BSTAGE_UNITS + q * 3 * 512 + wx * 4 * 64 + lane;
            bf16x8 Bh[4], Bm[4], Bl[4];
            #pragma unroll
            for (int nt = 0; nt < 4; ++nt) {
                Bh[nt] = Bq[nt * 64];
                Bm[nt] = Bq[512 + nt * 64];
                Bl[nt] = Bq[1024 + nt * 64];
            }
            // in-register split (VALU, overlaps MFMA pipe)
            bf16x8 Ah0, Am0, Al0, Ah1, Am1, Al1;
            split8(xa0, xb0, Ah0, Am0, Al0);
            split8(xa1, xb1, Ah1, Am1, Al1);
            #pragma unroll
            for (int nt = 0; nt < 4; ++nt) {
                acc[0][nt] = __builtin_amdgcn_mfma_f32_32x32x16_bf16(Ah0, Bh[nt], acc[0][nt], 0, 0, 0);
                acc[0][nt] = __builtin_amdgcn_mfma_f32_32x32x16_bf16(Ah0, Bm[nt], acc[0][nt], 0, 0, 0);
                acc[0][nt] = __builtin_amdgcn_mfma_f32_32x32x16_bf16(Am0, Bh[nt], acc[0][nt], 0, 0, 0);
                acc[0][nt] = __builtin_amdgcn_mfma_f32_32x32x16_bf16(Ah0, Bl[nt], acc[0][nt], 0, 0, 0);
                acc[0][nt] = __builtin_amdgcn_mfma_f32_32x32x16_bf16(Al0, Bh[nt], acc[0][nt], 0, 0, 0);
                acc[0][nt] = __builtin_amdgcn_mfma_f32_32x32x16_bf16(Am0, Bm[nt], acc[0][nt], 0, 0, 0);
            }
            #pragma unroll
            for (int nt = 0; nt < 4; ++nt) {
                acc[1][nt] = __builtin_amdgcn_mfma_f32_32x32x16_bf16(Ah1, Bh[nt], acc[1][nt], 0, 0, 0);
                acc[1][nt] = __builtin_amdgcn_mfma_f32_32x32x16_bf16(Ah1, Bm[nt], acc[1][nt], 0, 0, 0);
                acc[1][nt] = __builtin_amdgcn_mfma_f32_32x32x16_bf16(Am1, Bh[nt], acc[1][nt], 0, 0, 0);
                acc[1][nt] = __builtin_amdgcn_mfma_f32_32x32x16_bf16(Ah1, Bl[nt], acc[1][nt], 0, 0, 0);
                acc[1][nt] = __builtin_amdgcn_mfma_f32_32x32x16_bf16(Al1, Bh[nt], acc[1][nt], 0, 0, 0);
                acc[1][nt] = __builtin_amdgcn_mfma_f32_32x32x16_bf16(Am1, Bm[nt], acc[1][nt], 0, 0, 0);
            }
        }
    }

    // ---- epilogue: per-row score partial = sum_cols relu(h+b1)*W2
    float bb[4], ww[4];
    #pragma unroll
    for (int nt = 0; nt < 4; ++nt) {
        const int c = wx * 128 + nt * 32 + l31;
        bb[nt] = b1[c];
        ww[nt] = W2[c];
    }
    #pragma unroll
    for (int mt = 0; mt < 2; ++mt) {
        float pr[16];
        #pragma unroll
        for (int rr = 0; rr < 16; ++rr) pr[rr] = 0.f;
        #pragma unroll
        for (int nt = 0; nt < 4; ++nt)
            #pragma unroll
            for (int rr = 0; rr < 16; ++rr) {
                float h = acc[mt][nt][rr] + bb[nt];
                h = h > 0.f ? h : 0.f;
                pr[rr] = fmaf(h, ww[nt], pr[rr]);
            }
        #pragma unroll
        for (int mask = 1; mask <= 16; mask <<= 1)
            #pragma unroll
            for (int rr = 0; rr < 16; ++rr)
                pr[rr] += __shfl_xor(pr[rr], mask);
        if (l31 == 0) {
            #pragma unroll
            for (int rr = 0; rr < 16; ++rr) {
                const int row = wy * 64 + mt * 32 + (rr & 3) + 8 * (rr >> 2) + 4 * lh;
                Sp[wx * NPG + row] = pr[rr];
            }
        }
    }
    __syncthreads();

    float sc = 0.f;
    if (tid < NPG) {
        sc = b2[0] + Sp[tid] + Sp[NPG + tid];
        sv[tid] = sc;
    }
    __syncthreads();

    // selection: exact rank (score desc, index asc on ties)
    if (tid < NPG) {
        int rank = 0;
        for (int j = 0; j < NPG; ++j) {
            const float sj = sv[j];
            rank += (sj > sc || (sj == sc && j < tid)) ? 1 : 0;
        }
        const bool sel = rank < KSEL;
        mask_out[g * NPG + tid] = sel ? 1.0f : 0.0f;
        if (sel) selr[rank] = tid;
        redT[tid] = sc;
        redS[tid] = sel ? sc : 0.f;
    }
    __syncthreads();

    for (int off = 128; off > 0; off >>= 1) {
        if (tid < off) { redT[tid] += redT[tid + off]; redS[tid] += redS[tid + off]; }
        __syncthreads();
    }
    if (tid == 0) {
        const float tot = redT[0], ssum = redS[0];
        const float sel_mean = ssum * (1.0f / KSEL);
        const float uns_mean = (tot - ssum) * (1.0f / (NPG - KSEL));
        const float v = 0.5f - (sel_mean - uns_mean);
        loss_per_g[g] = v > 0.f ? v : 0.f;
    }

    // pooled gather; col per thread, rows L2/L3-warm
    const int col = tid;
    const float* __restrict__ xg = x + (size_t)g * NPG * FDIM;
    float a0 = 0.f, a1 = 0.f, a2 = 0.f, a3 = 0.f;
    #pragma unroll 4
    for (int n = 0; n < KSEL; n += 4) {
        a0 += xg[(size_t)selr[n + 0] * FDIM + col];
        a1 += xg[(size_t)selr[n + 1] * FDIM + col];
        a2 += xg[(size_t)selr[n + 2] * FDIM + col];
        a3 += xg[(size_t)selr[n + 3] * FDIM + col];
    }
    pooled[g * FDIM + col] = (a0 + a1) + (a2 + a3);
}

// ---------------------------------------------------------------------------
// K2: topk_loss = sum(loss_per_g) / B * 0.2
// ---------------------------------------------------------------------------
__global__ __launch_bounds__(256)
void loss_kernel(const float* __restrict__ loss_per_g, float* __restrict__ out_loss)
{
    __shared__ float red[256];
    const int t = threadIdx.x;
    red[t] = loss_per_g[t] + loss_per_g[t + 256];
    __syncthreads();
    for (int off = 128; off > 0; off >>= 1) {
        if (t < off) red[t] += red[t + off];
        __syncthreads();
    }
    if (t == 0) out_loss[0] = red[0] * (0.2f / BGRAPHS);
}

extern "C" void kernel_launch(void* const* d_in, const int* in_sizes, int n_in,
                              void* d_out, int out_size, void* d_ws, size_t ws_size,
                              hipStream_t stream)
{
    const float* x  = (const float*)d_in[0];
    const float* W1 = (const float*)d_in[2];
    const float* b1 = (const float*)d_in[3];
    const float* W2 = (const float*)d_in[4];
    const float* b2 = (const float*)d_in[5];

    float* out    = (float*)d_out;
    float* pooled = out;                       // [512*512]
    float* loss   = out + BGRAPHS * FDIM;      // [1]
    float* mask   = loss + 1;                  // [131072]

    float* loss_g       = (float*)d_ws;                               // 2 KB
    unsigned short* wsB = (unsigned short*)((char*)d_ws + 4096);      // 768 KB

    split_w1_kernel<<<192, 256, 0, stream>>>(W1, wsB);
    fused_kernel<<<BGRAPHS, 512, 0, stream>>>(x, wsB, b1, W2, b2,
                                              pooled, mask, loss_g);
    loss_kernel<<<1, 256, 0, stream>>>(loss_g, loss);
}